// Round 11
// baseline (154.633 us; speedup 1.0000x reference)
//
#include <hip/hip_runtime.h>
#include <cmath>

#define Bsz 4
#define Ssz 2048
#define Dsz 512
#define Hn 8

typedef unsigned short u16;
typedef _Float16 f16;
typedef __attribute__((ext_vector_type(4))) _Float16 f16x4;
typedef __attribute__((ext_vector_type(8))) _Float16 f16x8;
typedef __attribute__((ext_vector_type(8))) unsigned short us8;
typedef __attribute__((ext_vector_type(4))) float f32x4;
typedef __attribute__((ext_vector_type(16))) float f32x16;

__device__ __forceinline__ void gl2lds16(const void* g, void* l) {
    __builtin_amdgcn_global_load_lds(
        (const __attribute__((address_space(1))) void*)g,
        (__attribute__((address_space(3))) void*)l, 16, 0, 0);
}

// ---- fused prep: blocks [0,2048) convert x (fp32->fp16, 8/thread);
//      blocks [2048,2304) transpose+convert weights.
//      Wq/bq folded scale = (1/8)*log2(e) -> attn softmax runs in exp2 domain.
__global__ __launch_bounds__(256) void prep(const float* __restrict__ x,
                                            f16* __restrict__ xb,
                                            const float* __restrict__ Wq,
                                            const float* __restrict__ Wk,
                                            const float* __restrict__ Wv,
                                            const float* __restrict__ Wo,
                                            f16* __restrict__ Wtqkv,
                                            f16* __restrict__ Wto) {
    const int blk = blockIdx.x;
    const int tid = threadIdx.x;
    if (blk < 2048) {
        int i = blk * 256 + tid;
        const float4* xv = (const float4*)x;
        float4 a = xv[2 * i], b = xv[2 * i + 1];
        f16x8 o;
        o[0] = (f16)a.x; o[1] = (f16)a.y; o[2] = (f16)a.z; o[3] = (f16)a.w;
        o[4] = (f16)b.x; o[5] = (f16)b.y; o[6] = (f16)b.z; o[7] = (f16)b.w;
        ((f16x8*)xb)[i] = o;
        return;
    }
    __shared__ float T[64][65];
    const int bz = blk - 2048;             // 256 blocks: 8 x 8 x 4
    const int z = bz >> 6;
    const int n0 = (bz & 7) * 64, k0 = ((bz >> 3) & 7) * 64;
    const float* W = (z == 0) ? Wq : (z == 1) ? Wk : (z == 2) ? Wv : Wo;
    const float sc = (z == 0) ? 0.18033688f : 1.0f;  // (1/8)*log2e into Wq
#pragma unroll
    for (int i = 0; i < 16; i++) {
        int e = tid + i * 256;
        int r = e >> 6, c = e & 63;
        T[r][c] = W[(size_t)(k0 + r) * Dsz + n0 + c];
    }
    __syncthreads();
    f16* dst = (z < 3) ? (Wtqkv + ((size_t)z * 512 + n0) * Dsz + k0)
                       : (Wto + (size_t)n0 * Dsz + k0);
#pragma unroll
    for (int i = 0; i < 16; i++) {
        int e = tid + i * 256;
        int r = e >> 6, c = e & 63;
        dst[(size_t)r * Dsz + c] = (f16)(T[c][r] * sc);
    }
}

// ---- 128x128-tile fp16 MFMA GEMM (32x32x16), BK=32, double-buffered K-loop.
// C = relu(A @ Bt^T + bias).
// MODE 0: Q -> row-major (pre-scaled); K -> packed [bh][t][i][d];
//         V -> packed V^T [bh][t][d][i] (LDS transpose). MODE 1: fp32 out.
template <int MODE>
__global__ __launch_bounds__(256) void gemm128(
    const f16* __restrict__ A, const f16* __restrict__ Bt,
    u16* o0, u16* o1, u16* o2v,
    const float* b0, const float* b1, const float* b2,
    float* ofp, const float* bias_f) {
    // 4 buffers of 4096 u16 (8KB): As0|As1|Bs0|Bs1 = 32KB total
    __shared__ __align__(16) u16 smem[4 * 4096];
    const int tid = threadIdx.x;
    const int colg0 = blockIdx.x * 128;
    const int row0 = blockIdx.y * 128;
    const int w = tid >> 6, lane = tid & 63;
    const int nn = lane & 31, hh = lane >> 5;
    const int wr = w >> 1, wc = w & 1;

    f32x16 acc[2][2];
#pragma unroll
    for (int bi = 0; bi < 2; bi++)
#pragma unroll
        for (int bj = 0; bj < 2; bj++)
#pragma unroll
            for (int e = 0; e < 16; e++) acc[bi][bj][e] = 0.f;

    const f16* Ablk = A + (size_t)row0 * 512;
    const f16* Bblk = Bt + (size_t)colg0 * 512;

    // Staging (BK=32): 512 chunks of 16B per matrix. LDS line L (128B) holds
    // rows {2L,2L+1}; chunk slot p=L*8+c8s holds source c8 = c8s^(L&7),
    // row = 2L+(c8>>2), kc = c8&3. Dest is linear in tid (gl2lds constraint).
#define GSTAGE(k0_, ab)                                                        \
    {                                                                          \
        _Pragma("unroll") for (int i = 0; i < 2; i++) {                        \
            int p = tid + i * 256;                                             \
            int L = p >> 3, c8 = (p & 7) ^ (L & 7);                            \
            int m = 2 * L + (c8 >> 2), kc = c8 & 3;                            \
            gl2lds16(Ablk + (size_t)m * 512 + (k0_) + kc * 8,                  \
                     smem + (ab) * 4096 + p * 8);                              \
            gl2lds16(Bblk + (size_t)m * 512 + (k0_) + kc * 8,                  \
                     smem + 8192 + (ab) * 4096 + p * 8);                       \
        }                                                                      \
    }

    // fragment address for row r, k-chunk kc within a buffer
#define FRAG(bufbase, r, kc)                                                   \
    (*(const f16x8*)(smem + (bufbase) +                                        \
                     (((r) >> 1) * 8 + ((((r) & 1) * 4 + (kc)) ^ (((r) >> 1) & 7))) * 8))

#define GCOMPUTE(ab)                                                           \
    {                                                                          \
        _Pragma("unroll") for (int t = 0; t < 2; t++) {                        \
            f16x8 af[2], bfr[2];                                               \
            _Pragma("unroll") for (int bi = 0; bi < 2; bi++) {                 \
                int r = wr * 64 + bi * 32 + nn;                                \
                af[bi] = FRAG((ab) * 4096, r, t * 2 + hh);                     \
            }                                                                  \
            _Pragma("unroll") for (int bj = 0; bj < 2; bj++) {                 \
                int n = wc * 64 + bj * 32 + nn;                                \
                bfr[bj] = FRAG(8192 + (ab) * 4096, n, t * 2 + hh);             \
            }                                                                  \
            _Pragma("unroll") for (int bi = 0; bi < 2; bi++)                   \
                _Pragma("unroll") for (int bj = 0; bj < 2; bj++)               \
                    acc[bi][bj] = __builtin_amdgcn_mfma_f32_32x32x16_f16(      \
                        af[bi], bfr[bj], acc[bi][bj], 0, 0, 0);                \
        }                                                                      \
    }

    GSTAGE(0, 0)
    for (int k0 = 0; k0 < 512; k0 += 64) {
        __syncthreads();                       // buf0 staged; buf1 free
        GSTAGE(k0 + 32, 1)                     // prefetch overlaps compute
        GCOMPUTE(0)
        __syncthreads();                       // buf1 staged; buf0 free
        if (k0 + 64 < 512) GSTAGE(k0 + 64, 0)
        GCOMPUTE(1)
    }
#undef GSTAGE
#undef FRAG
#undef GCOMPUTE

    // C/D mapping (m74/m101): col = nn, rowoff = (reg&3) + 8*(reg>>2) + 4*hh
    if (MODE == 0) {
        const int sel = colg0 >> 9;           // 0=Q, 1=K, 2=V
        const int c0 = colg0 & 511;
        if (sel < 2) {                        // Q/K: direct stores
            u16* outp = (sel == 0) ? o0 : o1;
            const float* bp = (sel == 0) ? b0 : b1;
            const float bscale = (sel == 0) ? 0.18033688f : 1.0f;
#pragma unroll
            for (int bj = 0; bj < 2; bj++) {
                int col = c0 + wc * 64 + bj * 32 + nn;
                float bv = bp[col] * bscale;
                int head = col >> 6, dd = col & 63;
#pragma unroll
                for (int bi = 0; bi < 2; bi++)
#pragma unroll
                    for (int rg = 0; rg < 16; rg++) {
                        int row = row0 + wr * 64 + bi * 32 +
                                  (rg & 3) + 8 * (rg >> 2) + 4 * hh;
                        f16 v = (f16)fmaxf(acc[bi][bj][rg] + bv, 0.f);
                        size_t dst;
                        if (sel == 0) {
                            dst = (size_t)row * 512 + col;
                        } else {              // packed K [bh][t][i][d]
                            int bb = row >> 11, ss = row & 2047;
                            int tt = ss >> 6, ii = ss & 63;
                            dst = (((size_t)((bb * 8 + head) * 32 + tt)) << 12)
                                  + ii * 64 + dd;
                        }
                        *(f16*)(outp + dst) = v;
                    }
            }
        } else {                            // V: LDS transpose -> packed V^T tiles
            const int hh_head = c0 >> 6;    // first head of this col range
            f16 (*T)[136] = (f16(*)[136])smem;   // 64 x 136 fp16 (17.4KB)
            const int bb = row0 >> 11;
            const int t0 = (row0 & 2047) >> 6;
            __syncthreads();                // all waves done reading smem bufs
#pragma unroll
            for (int ph = 0; ph < 2; ph++) {
                if (wc == ph) {
#pragma unroll
                    for (int bj = 0; bj < 2; bj++) {
                        int d = bj * 32 + nn;
                        float bv = b2[c0 + ph * 64 + d];
#pragma unroll
                        for (int bi = 0; bi < 2; bi++)
#pragma unroll
                            for (int rg = 0; rg < 16; rg++) {
                                int s = wr * 64 + bi * 32 +
                                        (rg & 3) + 8 * (rg >> 2) + 4 * hh;
                                T[d][s] = (f16)fmaxf(acc[bi][bj][rg] + bv, 0.f);
                            }
                    }
                }
                __syncthreads();
#pragma unroll
                for (int ii = 0; ii < 4; ii++) {
                    int oct = tid + ii * 256;        // 1024 octets = 2 tiles
                    int tt = oct >> 9, rem = oct & 511;
                    int d = rem >> 3, s8 = rem & 7;
                    us8 val = *(const us8*)(&T[d][tt * 64 + s8 * 8]);
                    size_t dst = (((size_t)((bb * 8 + hh_head + ph) * 32 + t0 + tt)) << 12)
                                 + d * 64 + s8 * 8;
                    *(us8*)(o2v + dst) = val;
                }
                __syncthreads();
            }
        }
    } else {
#pragma unroll
        for (int bj = 0; bj < 2; bj++) {
            int col = colg0 + wc * 64 + bj * 32 + nn;
            float bv = bias_f[col];
#pragma unroll
            for (int bi = 0; bi < 2; bi++)
#pragma unroll
                for (int rg = 0; rg < 16; rg++) {
                    int row = row0 + wr * 64 + bi * 32 +
                              (rg & 3) + 8 * (rg >> 2) + 4 * hh;
                    ofp[(size_t)row * 512 + col] = fmaxf(acc[bi][bj][rg] + bv, 0.f);
                }
        }
    }
}

// ---- flash attention: 128 queries/block, packed K and V^T tiles,
//      S^T-in-register (QK^T via 16x16x32), exp2-domain fixed-shift softmax ----
__global__ __launch_bounds__(512) void attn_mfma(
    const f16* __restrict__ Q, const u16* __restrict__ KP,
    const u16* __restrict__ VT, const int* __restrict__ G,
    f16* __restrict__ Y) {
    __shared__ __align__(16) u16 Ks[2][4096];   // frag-image, XOR-swizzled
    __shared__ __align__(16) u16 Vs[2][4096];

    const int qt = blockIdx.x, h = blockIdx.y, b = blockIdx.z;
    const int q0 = qt * 128;
    const int tid = threadIdx.x;
    const int w = tid >> 6, lane = tid & 63;
    const int ln = lane & 15, quad = lane >> 4;

    const f16* Qb = Q + (size_t)b * Ssz * Dsz;
    const u16* Ktb = KP + (size_t)(b * Hn + h) * 32 * 4096;
    const u16* Vtb = VT + (size_t)(b * Hn + h) * 32 * 4096;
    const int* Gb = G + (size_t)b * Ssz;

    // Q B-frags for 16x16x32 (n=ln, k=quad*8+j); Q pre-scaled by 0.125*log2e
    f16x8 qf[2];
    {
        const f16* qrow = Qb + (size_t)(q0 + w * 16 + ln) * Dsz + h * 64;
        qf[0] = *(const f16x8*)(qrow + quad * 8);
        qf[1] = *(const f16x8*)(qrow + 32 + quad * 8);
    }
    const int gq = Gb[q0 + w * 16 + ln];
    const int gqmin = Gb[q0], gqmax = Gb[q0 + 127];

    // visited tile range (sorted groups => contiguous)
    int gf = 0, gl = 0; bool ov = false;
    if (lane < 32) {
        gf = Gb[lane * 64]; gl = Gb[lane * 64 + 63];
        ov = (gl >= gqmin) && (gf <= gqmax);
    }
    unsigned long long mask = __ballot(ov);
    const int kt_lo = __builtin_ctzll(mask);
    const int kt_hi = 63 - __builtin_clzll(mask);

    f32x4 o[4];
    const f32x4 z4 = {0.f, 0.f, 0.f, 0.f};
#pragma unroll
    for (int nd = 0; nd < 4; nd++) o[nd] = z4;
    float lsum = 0.f;

    // staging: 512 chunks of 16B from packed 8KB tiles (fully sequential)
#define STAGE_T(base, kt, dstbuf)                                              \
    {                                                                          \
        const u16* tile = (base) + (size_t)(kt) * 4096;                        \
        int row = tid >> 3, c = tid & 7;                                       \
        gl2lds16(tile + row * 64 + ((c ^ (row & 7)) << 3),                     \
                 (dstbuf) + tid * 8);                                          \
    }

    STAGE_T(Ktb, kt_lo, Ks[0])
    STAGE_T(Vtb, kt_lo, Vs[0])

    int buf = 0;
    for (int kt = kt_lo; kt <= kt_hi; kt++) {
        __syncthreads();                 // buf ready; all waves off buf^1
        if (kt < kt_hi) {
            STAGE_T(Ktb, kt + 1, Ks[buf ^ 1])
            STAGE_T(Vtb, kt + 1, Vs[buf ^ 1])
        }
        const u16* ks = Ks[buf];
        const u16* vs = Vs[buf];
        const int k0 = kt * 64;
        const int gkf = __shfl(gf, kt), gkl = __shfl(gl, kt);
        const bool needMask = !(gqmin == gqmax && gkf == gkl);

        f16x4 pf[4];
#pragma unroll
        for (int kb = 0; kb < 4; kb++) {
            f32x4 s = z4;
#pragma unroll
            for (int kk = 0; kk < 2; kk++) {   // S^T = K Q^T, K=32 per mfma
                int key = kb * 16 + ln;
                int ch = key * 8 + ((kk * 4 + quad) ^ (key & 7));
                f16x8 kf = *(const f16x8*)(ks + ch * 8);
                s = __builtin_amdgcn_mfma_f32_16x16x32_f16(kf, qf[kk], s, 0, 0, 0);
            }
            float sv[4];
            if (needMask) {
                int4 g4 = *(const int4*)(Gb + k0 + kb * 16 + quad * 4);
                sv[0] = (gq == g4.x) ? s[0] - 5.7708f : -1e9f;
                sv[1] = (gq == g4.y) ? s[1] - 5.7708f : -1e9f;
                sv[2] = (gq == g4.z) ? s[2] - 5.7708f : -1e9f;
                sv[3] = (gq == g4.w) ? s[3] - 5.7708f : -1e9f;
            } else {
#pragma unroll
                for (int r = 0; r < 4; r++) sv[r] = s[r] - 5.7708f;
            }
            f16x4 pp;
#pragma unroll
            for (int r = 0; r < 4; r++) {
                float e = exp2f(sv[r]);        // single v_exp_f32
                lsum += e;
                pp[r] = (f16)e;
            }
            pf[kb] = pp;
        }
        // O += P V   (P regs are already the A-operand layout for x16)
#pragma unroll
        for (int nd = 0; nd < 4; nd++)
#pragma unroll
            for (int kc = 0; kc < 4; kc++) {
                int addr = (((nd * 16 + ln) * 8 +
                             ((kc * 2 + (quad >> 1)) ^ (ln & 7))) << 3) +
                           (quad & 1) * 4;
                f16x4 vf = *(const f16x4*)(vs + addr);
                o[nd] = __builtin_amdgcn_mfma_f32_16x16x16f16(pf[kc], vf, o[nd], 0, 0, 0);
            }
        buf ^= 1;
    }

    lsum += __shfl_xor(lsum, 16);
    lsum += __shfl_xor(lsum, 32);
    float linv = 1.0f / lsum;
#pragma unroll
    for (int r = 0; r < 4; r++) {
        float lr = __shfl(linv, (lane & 48) | (quad * 4 + r));
        size_t row = (size_t)b * Ssz + q0 + w * 16 + quad * 4 + r;
#pragma unroll
        for (int nd = 0; nd < 4; nd++)
            Y[row * Dsz + h * 64 + nd * 16 + ln] = (f16)(o[nd][r] * lr);
    }
#undef STAGE_T
}

extern "C" void kernel_launch(void* const* d_in, const int* in_sizes, int n_in,
                              void* d_out, int out_size, void* d_ws, size_t ws_size,
                              hipStream_t stream) {
    const float* x  = (const float*)d_in[0];
    const int*   g  = (const int*)d_in[1];
    const float* Wq = (const float*)d_in[2];
    const float* bq = (const float*)d_in[3];
    const float* Wk = (const float*)d_in[4];
    const float* bk = (const float*)d_in[5];
    const float* Wv = (const float*)d_in[6];
    const float* bv = (const float*)d_in[7];
    const float* Wo = (const float*)d_in[8];
    const float* bo = (const float*)d_in[9];
    float* out = (float*)d_out;

    const size_t E = (size_t)Bsz * Ssz * Dsz;   // 4M elements
    f16* xb  = (f16*)d_ws;
    f16* qb  = xb + E;                  // [B,S,D] fp16 (pre-scaled)
    u16* kpb = (u16*)(qb + E);          // packed K [bh][t][i][d]
    u16* vtb = kpb + E;                 // packed V^T [bh][t][d][i]
    f16* yb  = (f16*)(vtb + E);         // [B,S,D] fp16
    f16* Wtqkv = yb + E;                // [1536][512]
    f16* Wto   = Wtqkv + 1536 * 512;    // [512][512]

    prep<<<2304, 256, 0, stream>>>(x, xb, Wq, Wk, Wv, Wo, Wtqkv, Wto);
    gemm128<0><<<dim3(12, 64), 256, 0, stream>>>(xb, Wtqkv, (u16*)qb, kpb, vtb,
                                                 bq, bk, bv, nullptr, nullptr);
    attn_mfma<<<dim3(Ssz / 128, Hn, Bsz), 512, 0, stream>>>(qb, kpb, vtb, g, yb);
    gemm128<1><<<dim3(4, 64), 256, 0, stream>>>(yb, Wto, nullptr, nullptr, nullptr,
                                                nullptr, nullptr, nullptr,
                                                out, bo);
}

// Round 12
// 152.556 us; speedup vs baseline: 1.0136x; 1.0136x over previous
//
#include <hip/hip_runtime.h>
#include <cmath>

#define Bsz 4
#define Ssz 2048
#define Dsz 512
#define Hn 8

typedef unsigned short u16;
typedef _Float16 f16;
typedef __attribute__((ext_vector_type(4))) _Float16 f16x4;
typedef __attribute__((ext_vector_type(8))) _Float16 f16x8;
typedef __attribute__((ext_vector_type(8))) unsigned short us8;
typedef __attribute__((ext_vector_type(4))) float f32x4;
typedef __attribute__((ext_vector_type(16))) float f32x16;

__device__ __forceinline__ void gl2lds16(const void* g, void* l) {
    __builtin_amdgcn_global_load_lds(
        (const __attribute__((address_space(1))) void*)g,
        (__attribute__((address_space(3))) void*)l, 16, 0, 0);
}

// first index i in sorted a[0..2048) with a[i] >= v (i may be 2048)
__device__ __forceinline__ int lbound2k(const int* __restrict__ a, int v) {
    int lo = 0;
#pragma unroll
    for (int step = 2048; step > 0; step >>= 1)
        if (lo + step <= 2048 && a[lo + step - 1] < v) lo += step;
    return lo;
}

// ---- fused prep: blocks [0,2048) convert x (fp32->fp16, 8/thread);
//      blocks [2048,2304) transpose+convert weights.
//      Wq/bq folded scale = (1/8)*log2(e) -> softmax in exp2 domain.
__global__ __launch_bounds__(256) void prep(const float* __restrict__ x,
                                            f16* __restrict__ xb,
                                            const float* __restrict__ Wq,
                                            const float* __restrict__ Wk,
                                            const float* __restrict__ Wv,
                                            const float* __restrict__ Wo,
                                            f16* __restrict__ Wtqkv,
                                            f16* __restrict__ Wto) {
    const int blk = blockIdx.x;
    const int tid = threadIdx.x;
    if (blk < 2048) {
        int i = blk * 256 + tid;
        const float4* xv = (const float4*)x;
        float4 a = xv[2 * i], b = xv[2 * i + 1];
        f16x8 o;
        o[0] = (f16)a.x; o[1] = (f16)a.y; o[2] = (f16)a.z; o[3] = (f16)a.w;
        o[4] = (f16)b.x; o[5] = (f16)b.y; o[6] = (f16)b.z; o[7] = (f16)b.w;
        ((f16x8*)xb)[i] = o;
        return;
    }
    __shared__ float T[64][65];
    const int bz = blk - 2048;             // 256 blocks: 8 x 8 x 4
    const int z = bz >> 6;
    const int n0 = (bz & 7) * 64, k0 = ((bz >> 3) & 7) * 64;
    const float* W = (z == 0) ? Wq : (z == 1) ? Wk : (z == 2) ? Wv : Wo;
    const float sc = (z == 0) ? 0.18033688f : 1.0f;  // (1/8)*log2e into Wq
#pragma unroll
    for (int i = 0; i < 16; i++) {
        int e = tid + i * 256;
        int r = e >> 6, c = e & 63;
        T[r][c] = W[(size_t)(k0 + r) * Dsz + n0 + c];
    }
    __syncthreads();
    f16* dst = (z < 3) ? (Wtqkv + ((size_t)z * 512 + n0) * Dsz + k0)
                       : (Wto + (size_t)n0 * Dsz + k0);
#pragma unroll
    for (int i = 0; i < 16; i++) {
        int e = tid + i * 256;
        int r = e >> 6, c = e & 63;
        dst[(size_t)r * Dsz + c] = (f16)(T[c][r] * sc);
    }
}

// ---- 128x128-tile fp16 MFMA GEMM (32x32x16), C = relu(A @ Bt^T + bias) ----
// MODE 0: Q,K -> plain f16 row-major [B,S,D] (Q pre-scaled); V -> LDS-transposed
//         packed V^T [bh][t][d][i]. MODE 1: fp32 out row-major.
template <int MODE>
__global__ __launch_bounds__(256) void gemm128(
    const f16* __restrict__ A, const f16* __restrict__ Bt,
    u16* o0, u16* o1, u16* o2v,
    const float* b0, const float* b1, const float* b2,
    float* ofp, const float* bias_f) {
    __shared__ __align__(16) u16 smem[2 * 128 * 64];   // As | Bs ; reused as T
    u16* As = smem;
    u16* Bs = smem + 128 * 64;
    const int tid = threadIdx.x;
    const int colg0 = blockIdx.x * 128;
    const int row0 = blockIdx.y * 128;
    const int w = tid >> 6, lane = tid & 63;
    const int nn = lane & 31, hh = lane >> 5;
    const int wr = w >> 1, wc = w & 1;

    f32x16 acc[2][2];
#pragma unroll
    for (int bi = 0; bi < 2; bi++)
#pragma unroll
        for (int bj = 0; bj < 2; bj++)
#pragma unroll
            for (int e = 0; e < 16; e++) acc[bi][bj][e] = 0.f;

    const f16* Ablk = A + (size_t)row0 * 512;
    const f16* Bblk = Bt + (size_t)colg0 * 512;

    for (int k0 = 0; k0 < 512; k0 += 64) {
        __syncthreads();
#pragma unroll
        for (int i = 0; i < 4; i++) {
            int p = tid + i * 256;           // 16B chunk id
            int m = p >> 3, kc = p & 7;
            int gk = ((kc ^ (m & 7)) << 3);  // XOR-swizzled k origin
            gl2lds16(Ablk + (size_t)m * 512 + k0 + gk, As + p * 8);
            gl2lds16(Bblk + (size_t)m * 512 + k0 + gk, Bs + p * 8);
        }
        __syncthreads();
#pragma unroll
        for (int t = 0; t < 4; t++) {        // four 32x32x16 k-steps
            f16x8 af[2], bfr[2];
#pragma unroll
            for (int bi = 0; bi < 2; bi++) {
                int r = wr * 64 + bi * 32 + nn;
                int ch = r * 8 + ((t * 2 + hh) ^ (r & 7));
                af[bi] = *(const f16x8*)(As + ch * 8);
            }
#pragma unroll
            for (int bj = 0; bj < 2; bj++) {
                int n = wc * 64 + bj * 32 + nn;
                int ch = n * 8 + ((t * 2 + hh) ^ (n & 7));
                bfr[bj] = *(const f16x8*)(Bs + ch * 8);
            }
#pragma unroll
            for (int bi = 0; bi < 2; bi++)
#pragma unroll
                for (int bj = 0; bj < 2; bj++)
                    acc[bi][bj] = __builtin_amdgcn_mfma_f32_32x32x16_f16(
                        af[bi], bfr[bj], acc[bi][bj], 0, 0, 0);
        }
    }

    // C/D mapping (m74/m101): col = nn, rowoff = (reg&3) + 8*(reg>>2) + 4*hh
    if (MODE == 0) {
        const int sel = colg0 >> 9;           // 0=Q, 1=K, 2=V
        const int c0 = colg0 & 511;
        if (sel < 2) {                        // Q/K: direct row-major stores
            u16* outp = (sel == 0) ? o0 : o1;
            const float* bp = (sel == 0) ? b0 : b1;
            const float bscale = (sel == 0) ? 0.18033688f : 1.0f;
#pragma unroll
            for (int bj = 0; bj < 2; bj++) {
                int col = c0 + wc * 64 + bj * 32 + nn;
                float bv = bp[col] * bscale;
#pragma unroll
                for (int bi = 0; bi < 2; bi++)
#pragma unroll
                    for (int rg = 0; rg < 16; rg++) {
                        int row = row0 + wr * 64 + bi * 32 +
                                  (rg & 3) + 8 * (rg >> 2) + 4 * hh;
                        f16 v = (f16)fmaxf(acc[bi][bj][rg] + bv, 0.f);
                        *(f16*)(outp + (size_t)row * 512 + col) = v;
                    }
            }
        } else {                            // V: LDS transpose -> packed V^T tiles
            const int hh_head = c0 >> 6;    // first head of this col range
            f16 (*T)[136] = (f16(*)[136])smem;   // 64 x 136 fp16
            const int bb = row0 >> 11;
            const int t0 = (row0 & 2047) >> 6;
            __syncthreads();                // all waves done reading As/Bs
#pragma unroll
            for (int ph = 0; ph < 2; ph++) {
                if (wc == ph) {
#pragma unroll
                    for (int bj = 0; bj < 2; bj++) {
                        int d = bj * 32 + nn;
                        float bv = b2[c0 + ph * 64 + d];
#pragma unroll
                        for (int bi = 0; bi < 2; bi++)
#pragma unroll
                            for (int rg = 0; rg < 16; rg++) {
                                int s = wr * 64 + bi * 32 +
                                        (rg & 3) + 8 * (rg >> 2) + 4 * hh;
                                T[d][s] = (f16)fmaxf(acc[bi][bj][rg] + bv, 0.f);
                            }
                    }
                }
                __syncthreads();
#pragma unroll
                for (int ii = 0; ii < 4; ii++) {
                    int oct = tid + ii * 256;        // 1024 octets = 2 tiles
                    int tt = oct >> 9, rem = oct & 511;
                    int d = rem >> 3, s8 = rem & 7;
                    us8 val = *(const us8*)(&T[d][tt * 64 + s8 * 8]);
                    size_t dst = (((size_t)((bb * 8 + hh_head + ph) * 32 + t0 + tt)) << 12)
                                 + d * 64 + s8 * 8;
                    *(us8*)(o2v + dst) = val;
                }
                __syncthreads();
            }
        }
    } else {
#pragma unroll
        for (int bj = 0; bj < 2; bj++) {
            int col = colg0 + wc * 64 + bj * 32 + nn;
            float bv = bias_f[col];
#pragma unroll
            for (int bi = 0; bi < 2; bi++)
#pragma unroll
                for (int rg = 0; rg < 16; rg++) {
                    int row = row0 + wr * 64 + bi * 32 +
                              (rg & 3) + 8 * (rg >> 2) + 4 * hh;
                    ofp[(size_t)row * 512 + col] = fmaxf(acc[bi][bj][rg] + bv, 0.f);
                }
        }
    }
}

// ---- flash attention: 128 queries/block, S^T-in-register, exp2 softmax.
//      Contiguous group ranges via binary search (no G loads in hot loop),
//      per-wave tile skip. ----
__global__ __launch_bounds__(512) void attn_mfma(
    const f16* __restrict__ Q, const f16* __restrict__ K,
    const u16* __restrict__ VT, const int* __restrict__ G,
    f16* __restrict__ Y) {
    __shared__ __align__(16) u16 Ks[2][4096];   // frag-image, XOR-swizzled
    __shared__ __align__(16) u16 Vs[2][4096];

    const int qt = blockIdx.x, h = blockIdx.y, b = blockIdx.z;
    const int q0 = qt * 128;
    const int tid = threadIdx.x;
    const int w = tid >> 6, lane = tid & 63;
    const int ln = lane & 15, quad = lane >> 4;

    const f16* Qb = Q + (size_t)b * Ssz * Dsz;
    const f16* Kb = K + (size_t)b * Ssz * Dsz;
    const u16* Vtb = VT + (size_t)(b * Hn + h) * 32 * 4096;
    const int* Gb = G + (size_t)b * Ssz;

    // Q B-frags for 16x16x32 (n=ln, k=quad*8+j); Q pre-scaled by 0.125*log2e
    f16x8 qf[2];
    {
        const f16* qrow = Qb + (size_t)(q0 + w * 16 + ln) * Dsz + h * 64;
        qf[0] = *(const f16x8*)(qrow + quad * 8);
        qf[1] = *(const f16x8*)(qrow + 32 + quad * 8);
    }

    // contiguous valid-key range per query (groups sorted)
    const int gq = Gb[q0 + w * 16 + ln];
    const int qlo = lbound2k(Gb, gq);
    const int qhi = lbound2k(Gb, gq + 1);
    // per-wave and per-block key ranges
    const int wlo = __shfl(qlo, 0);       // lane 0 holds query w*16+0
    const int whi = __shfl(qhi, 15);      // lane 15 holds query w*16+15
    const int gqmin = Gb[q0], gqmax = Gb[q0 + 127];
    const int blo = lbound2k(Gb, gqmin);
    const int bhi = lbound2k(Gb, gqmax + 1);
    const int kt_lo = blo >> 6;
    const int kt_hi = (bhi - 1) >> 6;

    f32x4 o[4];
    const f32x4 z4 = {0.f, 0.f, 0.f, 0.f};
#pragma unroll
    for (int nd = 0; nd < 4; nd++) o[nd] = z4;
    float lsum = 0.f;

#define STAGE_K(kt, bi_)                                                       \
    {                                                                          \
        const f16* Ktile = Kb + (size_t)(kt) * 64 * Dsz + h * 64;              \
        int row = tid >> 3, c = tid & 7;                                       \
        gl2lds16(Ktile + (size_t)row * Dsz + ((c ^ (row & 7)) << 3),           \
                 Ks[bi_] + tid * 8);                                           \
    }
#define STAGE_V(kt, bi_)                                                       \
    {                                                                          \
        const u16* Vtile = Vtb + (size_t)(kt) * 4096;                          \
        int row = tid >> 3, c = tid & 7;                                       \
        gl2lds16(Vtile + row * 64 + ((c ^ (row & 7)) << 3),                    \
                 Vs[bi_] + tid * 8);                                           \
    }

    STAGE_K(kt_lo, 0)
    STAGE_V(kt_lo, 0)

    int buf = 0;
    for (int kt = kt_lo; kt <= kt_hi; kt++) {
        __syncthreads();                 // buf ready; all waves off buf^1
        if (kt < kt_hi) {
            STAGE_K(kt + 1, Ks[0] == Ks[0] ? buf ^ 1 : 0)
            STAGE_V(kt + 1, buf ^ 1)
        }
        const int k0 = kt * 64;
        if (k0 < whi && k0 + 64 > wlo) {     // wave-level tile skip
            const u16* ks = Ks[buf];
            const u16* vs = Vs[buf];

            f16x4 pf[4];
#pragma unroll
            for (int kb = 0; kb < 4; kb++) {
                f32x4 s = z4;
#pragma unroll
                for (int kk = 0; kk < 2; kk++) {   // S^T = K Q^T, K=32 per mfma
                    int key = kb * 16 + ln;
                    int ch = key * 8 + ((kk * 4 + quad) ^ (key & 7));
                    f16x8 kf = *(const f16x8*)(ks + ch * 8);
                    s = __builtin_amdgcn_mfma_f32_16x16x32_f16(kf, qf[kk], s, 0, 0, 0);
                }
                const int keybase = k0 + kb * 16 + quad * 4;
                f16x4 pp;
#pragma unroll
                for (int r = 0; r < 4; r++) {
                    int key = keybase + r;
                    float sv = (key >= qlo && key < qhi) ? s[r] - 5.7708f : -1e9f;
                    float e = exp2f(sv);
                    lsum += e;
                    pp[r] = (f16)e;
                }
                pf[kb] = pp;
            }
            // O += P V   (P regs are already the A-operand layout for x16)
#pragma unroll
            for (int nd = 0; nd < 4; nd++)
#pragma unroll
                for (int kc = 0; kc < 4; kc++) {
                    int addr = (((nd * 16 + ln) * 8 +
                                 ((kc * 2 + (quad >> 1)) ^ (ln & 7))) << 3) +
                               (quad & 1) * 4;
                    f16x4 vf = *(const f16x4*)(vs + addr);
                    o[nd] = __builtin_amdgcn_mfma_f32_16x16x16f16(pf[kc], vf, o[nd], 0, 0, 0);
                }
        }
        buf ^= 1;
    }

    lsum += __shfl_xor(lsum, 16);
    lsum += __shfl_xor(lsum, 32);
    float linv = 1.0f / lsum;
#pragma unroll
    for (int r = 0; r < 4; r++) {
        float lr = __shfl(linv, (lane & 48) | (quad * 4 + r));
        size_t row = (size_t)b * Ssz + q0 + w * 16 + quad * 4 + r;
#pragma unroll
        for (int nd = 0; nd < 4; nd++)
            Y[row * Dsz + h * 64 + nd * 16 + ln] = (f16)(o[nd][r] * lr);
    }
#undef STAGE_K
#undef STAGE_V
}

extern "C" void kernel_launch(void* const* d_in, const int* in_sizes, int n_in,
                              void* d_out, int out_size, void* d_ws, size_t ws_size,
                              hipStream_t stream) {
    const float* x  = (const float*)d_in[0];
    const int*   g  = (const int*)d_in[1];
    const float* Wq = (const float*)d_in[2];
    const float* bq = (const float*)d_in[3];
    const float* Wk = (const float*)d_in[4];
    const float* bk = (const float*)d_in[5];
    const float* Wv = (const float*)d_in[6];
    const float* bv = (const float*)d_in[7];
    const float* Wo = (const float*)d_in[8];
    const float* bo = (const float*)d_in[9];
    float* out = (float*)d_out;

    const size_t E = (size_t)Bsz * Ssz * Dsz;   // 4M elements
    f16* xb  = (f16*)d_ws;
    f16* qb  = xb + E;                  // [B,S,D] fp16 (pre-scaled)
    f16* kb2 = qb + E;                  // [B,S,D] fp16
    u16* vtb = (u16*)(kb2 + E);         // packed V^T [bh][t][d][i]
    f16* yb  = (f16*)(vtb + E);         // [B,S,D] fp16
    f16* Wtqkv = yb + E;                // [1536][512]
    f16* Wto   = Wtqkv + 1536 * 512;    // [512][512]

    prep<<<2304, 256, 0, stream>>>(x, xb, Wq, Wk, Wv, Wo, Wtqkv, Wto);
    gemm128<0><<<dim3(12, 64), 256, 0, stream>>>(xb, Wtqkv, (u16*)qb, (u16*)kb2, vtb,
                                                 bq, bk, bv, nullptr, nullptr);
    attn_mfma<<<dim3(Ssz / 128, Hn, Bsz), 512, 0, stream>>>(qb, kb2, vtb, g, yb);
    gemm128<1><<<dim3(4, 64), 256, 0, stream>>>(yb, Wto, nullptr, nullptr, nullptr,
                                                nullptr, nullptr, nullptr,
                                                out, bo);
}